// Round 3
// baseline (1855.267 us; speedup 1.0000x reference)
//
#include <hip/hip_runtime.h>
#include <hip/hip_bf16.h>

#define BDIM 2
#define SDIM 4096
#define EDIM 2048
#define TOK (BDIM * SDIM)       // 8192
#define QK_SCALE 0.08838834764831845f  // 128^-0.5

typedef short bf16x8 __attribute__((ext_vector_type(8)));
typedef float f32x4 __attribute__((ext_vector_type(4)));

__device__ __forceinline__ unsigned short f2bf(float f) {
    unsigned u = __float_as_uint(f);
    u += 0x7FFF + ((u >> 16) & 1);          // RNE; inputs finite
    return (unsigned short)(u >> 16);
}

// fp32x8 -> bf16 hi + bf16 lo (residual), for near-fp32 MFMA via 3-term split
__device__ __forceinline__ void cvt_split8(const float4 a, const float4 b,
                                           bf16x8& hi, bf16x8& lo) {
    float f[8] = {a.x, a.y, a.z, a.w, b.x, b.y, b.z, b.w};
#pragma unroll
    for (int i = 0; i < 8; ++i) {
        const unsigned short h = f2bf(f[i]);
        hi[i] = (short)h;
        const float hf = __uint_as_float(((unsigned)h) << 16);
        lo[i] = (short)f2bf(f[i] - hf);
    }
}

// async 16B global -> LDS (wave-uniform base + lane*16 dest; per-lane source ok)
__device__ __forceinline__ void cp16(const void* g, void* l) {
    __builtin_amdgcn_global_load_lds(
        (const __attribute__((address_space(1))) unsigned int*)g,
        (__attribute__((address_space(3))) unsigned int*)l, 16, 0, 0);
}

// LDS anti-bank-conflict involution: XOR row bits [3:1] (byte bits 9:7 at 64B
// rows) into byte bits [6:4]. 16B-granularity-preserving, self-inverse.
__device__ __forceinline__ int swz(int L) { return L ^ (((L >> 7) & 7) << 4); }

// ---- one-time fp32 -> bf16 hi/lo split (hoisted out of the GEMMs) ----
__global__ __launch_bounds__(256) void split_kernel(
    const float* __restrict__ x,
    unsigned short* __restrict__ xh, unsigned short* __restrict__ xl) {
    const long i = ((long)blockIdx.x * 256 + threadIdx.x) * 8;
    const float4 f0 = *(const float4*)(x + i);
    const float4 f1 = *(const float4*)(x + i + 4);
    bf16x8 hi, lo;
    cvt_split8(f0, f1, hi, lo);
    *(bf16x8*)(xh + i) = hi;
    *(bf16x8*)(xl + i) = lo;
}

// ============ deep-pipelined MFMA GEMM: C[m,n] = sum_seg A_seg B_seg^T ========
// Tile BM x 256, BK=32, 512 threads = 8 waves (2M x 4N), per-wave C = BM/2 x 64.
// Concatenated-K: nseg segments of length Kseg, per-segment A/B base pointers
// (hi/lo split products become plain segments: Ah*Bh, Ah*Bl, Al*Bh).
// 3 rotating LDS buffers; stage(t+2) issued in tile t body (targets buf of
// t-1, whose reads finished before the previous barrier -> race-free);
// s_waitcnt vmcnt(SOPS) keeps one stage-group in flight (never drains to 0
// until the epilogue); raw s_barrier (no implicit vmcnt(0) drain).
// LDS tiles are read-swizzled via swz(); cp16 sources are pre-swizzled so the
// linear LDS write + swizzled read form the same involution.
// EPI: 0 = fp32 store; 1 = bf16 store; 2 = kv-split (n<2048 bf16 Cp, n>=2048
// transposed bf16 Ct). C = (acc + bias[n]) * scale.
template <int BM, int EPI>
__global__ __launch_bounds__(512, 2) void gemm8(
    const unsigned short* __restrict__ A0, const unsigned short* __restrict__ A1,
    const unsigned short* __restrict__ A2, int lda,
    const unsigned short* __restrict__ B0, const unsigned short* __restrict__ B1,
    const unsigned short* __restrict__ B2, int ldb,
    void* __restrict__ Cp, int ldc, unsigned short* __restrict__ Ct, int ldt,
    const float* __restrict__ bias, float scale, int Kseg, int nseg) {

    constexpr int ABYTES = BM * 64;          // A tile: BM x 32 bf16
    constexpr int BBYTES = 256 * 64;         // B tile: 256 x 32 bf16
    constexpr int BUFB = ABYTES + BBYTES;
    constexpr int ASW = ABYTES / 8192;       // A staging sweeps (512 thr x 16B)
    constexpr int MT = BM / 32;              // m-fragments per wave
    __shared__ char lds[3 * BUFB];           // 96KB (BM=256) / 72KB (BM=128)

    const int tid = threadIdx.x;
    const int gx = gridDim.x;
    const int nwg = gx * gridDim.y;
    int bid = blockIdx.y * gx + blockIdx.x;
    bid = (bid & 7) * (nwg >> 3) + (bid >> 3);    // XCD swizzle (nwg % 8 == 0)
    const int n0 = (bid % gx) * 256;
    const int m0 = (bid / gx) * BM;

    const int lane = tid & 63;
    const int wave = tid >> 6;
    const int wr = wave >> 2;                // 0..1
    const int wc = wave & 3;                 // 0..3
    const int ln = lane & 15;
    const int quad = lane >> 4;

    const int tps = Kseg >> 5;               // K-tiles per segment
    const int NT = tps * nseg;

    auto stage = [&](int t) {
        const int seg = t / tps;
        const int kk = (t - seg * tps) * 32;
        const unsigned short* Ap = (seg == 0) ? A0 : ((seg == 1) ? A1 : A2);
        const unsigned short* Bp = (seg == 0) ? B0 : ((seg == 1) ? B1 : B2);
        char* buf = &lds[(t % 3) * BUFB];
#pragma unroll
        for (int s = 0; s < ASW; ++s) {
            const int L = s * 8192 + tid * 16;
            const int P = swz(L);            // source pre-swizzle (involution)
            cp16(Ap + (long)(m0 + (P >> 6)) * lda + kk + ((P & 63) >> 1),
                 buf + L);
        }
#pragma unroll
        for (int s = 0; s < 2; ++s) {
            const int L = s * 8192 + tid * 16;
            const int P = swz(L);
            cp16(Bp + (long)(n0 + (P >> 6)) * ldb + kk + ((P & 63) >> 1),
                 buf + ABYTES + L);
        }
    };

    f32x4 acc[MT][4] = {};

    // prologue: 2 tiles staged; wait tile0 (one stage-group of SOPS in flight)
    stage(0);
    stage(1);
    if constexpr (BM == 256) asm volatile("s_waitcnt vmcnt(4)" ::: "memory");
    else                     asm volatile("s_waitcnt vmcnt(3)" ::: "memory");
    __builtin_amdgcn_s_barrier();

    for (int t = 0; t < NT; ++t) {
        const char* buf = &lds[(t % 3) * BUFB];
        if (t + 2 < NT) stage(t + 2);        // targets buf of t-1: reads done

        bf16x8 bfr[4];
#pragma unroll
        for (int j = 0; j < 4; ++j) {
            const int L = (wc * 64 + j * 16 + ln) * 64 + quad * 16;
            bfr[j] = *(const bf16x8*)(buf + ABYTES + swz(L));
        }
        __builtin_amdgcn_s_setprio(1);
#pragma unroll
        for (int h = 0; h < 2; ++h) {
            bf16x8 afr[MT / 2];
#pragma unroll
            for (int i = 0; i < MT / 2; ++i) {
                const int row = wr * (BM / 2) + (h * (MT / 2) + i) * 16 + ln;
                const int L = row * 64 + quad * 16;
                afr[i] = *(const bf16x8*)(buf + swz(L));
            }
#pragma unroll
            for (int i = 0; i < MT / 2; ++i)
#pragma unroll
                for (int j = 0; j < 4; ++j)
                    acc[h * (MT / 2) + i][j] =
                        __builtin_amdgcn_mfma_f32_16x16x32_bf16(
                            afr[i], bfr[j], acc[h * (MT / 2) + i][j], 0, 0, 0);
        }
        __builtin_amdgcn_s_setprio(0);

        if (t + 1 < NT) {
            if (t + 2 < NT) {   // steady state: keep one stage-group in flight
                if constexpr (BM == 256)
                    asm volatile("s_waitcnt vmcnt(4)" ::: "memory");
                else
                    asm volatile("s_waitcnt vmcnt(3)" ::: "memory");
            } else {            // epilogue drain
                asm volatile("s_waitcnt vmcnt(0)" ::: "memory");
            }
            __builtin_amdgcn_s_barrier();
        }
    }

    // ---- epilogue: C/D layout col=lane&15, row=quad*4+reg ----
#pragma unroll
    for (int i = 0; i < MT; ++i) {
        const int gm = m0 + wr * (BM / 2) + i * 16 + quad * 4;   // rows gm..gm+3
#pragma unroll
        for (int j = 0; j < 4; ++j) {
            const int gn = n0 + wc * 64 + j * 16 + ln;
            const float bv = bias ? bias[gn] : 0.0f;
            const f32x4 d = acc[i][j];
            if (EPI == 2 && gn >= 2048) {
                const int bt = gm >> 12;
                const int rl = gm & 4095;
                ushort4 t4;
                t4.x = f2bf((d[0] + bv) * scale);
                t4.y = f2bf((d[1] + bv) * scale);
                t4.z = f2bf((d[2] + bv) * scale);
                t4.w = f2bf((d[3] + bv) * scale);
                *(ushort4*)&Ct[((long)bt * 2048 + (gn - 2048)) * ldt + rl] = t4;
            } else if (EPI == 0) {
                float* Cf = (float*)Cp;
#pragma unroll
                for (int r = 0; r < 4; ++r)
                    Cf[(long)(gm + r) * ldc + gn] = (d[r] + bv) * scale;
            } else {
                unsigned short* Cb = (unsigned short*)Cp;
#pragma unroll
                for (int r = 0; r < 4; ++r)
                    Cb[(long)(gm + r) * ldc + gn] = f2bf((d[r] + bv) * scale);
            }
        }
    }
}

// ---------- RoPE in-place on bf16 (TOK x ld), ld cols = 16 heads x 128 ----------
__global__ __launch_bounds__(256) void rope_kernel(__hip_bfloat16* __restrict__ p, int ld) {
    const long idx = (long)blockIdx.x * 256 + threadIdx.x;  // < TOK*1024
    const int m = (int)(idx >> 10);
    const int r = (int)(idx & 1023);
    const int h = r >> 6;
    const int i = r & 63;
    const int s = m & (SDIM - 1);
    const float f = (float)s * expf(-(float)i * 0.14391156831212787f);
    float cs, sn;
    sincosf(f, &sn, &cs);
    __hip_bfloat16* b = p + (long)m * ld + h * 128 + i;
    const float x1 = __bfloat162float(b[0]);
    const float x2 = __bfloat162float(b[64]);
    b[0]  = __float2bfloat16(x1 * cs - x2 * sn);
    b[64] = __float2bfloat16(x2 * cs + x1 * sn);
}

// ---------- row softmax over 4096: read fp32, write bf16 in place ----------
__global__ __launch_bounds__(256) void softmax_kernel(float* __restrict__ S) {
    const long row = blockIdx.x;
    float* p = S + row * 4096;
    const int tid = threadIdx.x;
    const int lane = tid & 63;
    const int w = tid >> 6;
    __shared__ float red[4];

    float x[16];
#pragma unroll
    for (int i = 0; i < 4; ++i) {
        const float4 v = reinterpret_cast<const float4*>(p)[i * 256 + tid];
        x[i * 4 + 0] = v.x; x[i * 4 + 1] = v.y; x[i * 4 + 2] = v.z; x[i * 4 + 3] = v.w;
    }
    float m = -1e30f;
#pragma unroll
    for (int i = 0; i < 16; ++i) m = fmaxf(m, x[i]);
#pragma unroll
    for (int off = 1; off < 64; off <<= 1) m = fmaxf(m, __shfl_xor(m, off));
    if (lane == 0) red[w] = m;
    __syncthreads();
    const float M = fmaxf(fmaxf(red[0], red[1]), fmaxf(red[2], red[3]));
    __syncthreads();

    float s = 0.0f;
#pragma unroll
    for (int i = 0; i < 16; ++i) { x[i] = __expf(x[i] - M); s += x[i]; }
#pragma unroll
    for (int off = 1; off < 64; off <<= 1) s += __shfl_xor(s, off);
    if (lane == 0) red[w] = s;
    __syncthreads();                 // all reads done before in-place bf16 write
    const float inv = 1.0f / (red[0] + red[1] + red[2] + red[3]);

    ushort4* dst = (ushort4*)p;      // bf16 packed into first half of the row
#pragma unroll
    for (int i = 0; i < 4; ++i) {
        ushort4 t;
        t.x = f2bf(x[i * 4 + 0] * inv); t.y = f2bf(x[i * 4 + 1] * inv);
        t.z = f2bf(x[i * 4 + 2] * inv); t.w = f2bf(x[i * 4 + 3] * inv);
        dst[i * 256 + tid] = t;
    }
}

extern "C" void kernel_launch(void* const* d_in, const int* in_sizes, int n_in,
                              void* d_out, int out_size, void* d_ws, size_t ws_size,
                              hipStream_t stream) {
    const float* x    = (const float*)d_in[0];
    const float* q_w  = (const float*)d_in[1];
    const float* q_b  = (const float*)d_in[2];
    const float* kv_w = (const float*)d_in[3];
    const float* kv_b = (const float*)d_in[4];
    const float* o_w  = (const float*)d_in[5];
    float* out = (float*)d_out;

    // ws (112 MiB, proven mapped), time-multiplexed:
    //   [0..32M)   qo slot: phase A = kv_w hi/lo split; phase B+ = q / o bf16
    //   [32..64M)  kb slot: K bf16; after last scores reused for o_w hi/lo
    //   [64..96M)  vT bf16 [2 x 2048 x 4096]
    //   [96..112M) q_w hi/lo split
    // d_out (64 MiB) triple-duty:
    //   phase 1: xh|xl bf16 hi/lo split of x
    //   phase 2: per-batch fp32 scores [4096 x 4096], softmax in place
    //   phase 3: final fp32 output (fully overwritten)
    unsigned short* qo  = (unsigned short*)d_ws;
    unsigned short* kb  = qo + (long)TOK * EDIM;
    unsigned short* vT  = kb + (long)TOK * EDIM;
    unsigned short* qwh = vT + (long)BDIM * EDIM * SDIM;
    unsigned short* qwl = qwh + (long)EDIM * EDIM;
    unsigned short* kvh = qo;
    unsigned short* kvl = kvh + (long)2 * EDIM * EDIM;
    unsigned short* owh = kb;
    unsigned short* owl = owh + (long)EDIM * EDIM;
    unsigned short* xh  = (unsigned short*)d_out;
    unsigned short* xl  = xh + (long)TOK * EDIM;
    const unsigned short* nil = nullptr;

    // 0) one-time hi/lo splits
    split_kernel<<<(long)TOK * EDIM / 2048, 256, 0, stream>>>(x, xh, xl);
    split_kernel<<<(long)2 * EDIM * EDIM / 2048, 256, 0, stream>>>(kv_w, kvh, kvl);

    // 1) kv = x @ kv_w^T + kv_b (3 segments: Ah*Bh, Ah*Bl, Al*Bh)
    gemm8<256, 2><<<dim3(16, 32), 512, 0, stream>>>(
        xh, xh, xl, EDIM, kvh, kvl, kvh, EDIM,
        kb, EDIM, vT, SDIM, kv_b, 1.0f, EDIM, 3);

    // 2) q = (x @ q_w^T + q_b) * scale
    split_kernel<<<(long)EDIM * EDIM / 2048, 256, 0, stream>>>(q_w, qwh, qwl);
    gemm8<256, 1><<<dim3(8, 32), 512, 0, stream>>>(
        xh, xh, xl, EDIM, qwh, qwl, qwh, EDIM,
        qo, EDIM, nullptr, 0, q_b, QK_SCALE, EDIM, 3);

    // 3) RoPE on q and k
    rope_kernel<<<(long)TOK * 1024 / 256, 256, 0, stream>>>((__hip_bfloat16*)qo, EDIM);
    rope_kernel<<<(long)TOK * 1024 / 256, 256, 0, stream>>>((__hip_bfloat16*)kb, EDIM);

    // 4) per-batch attention
    for (int b = 0; b < BDIM; ++b) {
        float* scb = (float*)d_out;                    // 4096 x 4096 fp32
        const long ro = (long)b * SDIM * EDIM;

        // scores = q_b @ k_b^T  (256 wgs)
        gemm8<256, 0><<<dim3(16, 16), 512, 0, stream>>>(
            qo + ro, nil, nil, EDIM, kb + ro, nil, nil, EDIM,
            scb, SDIM, nullptr, 0, nullptr, 1.0f, EDIM, 1);

        softmax_kernel<<<SDIM, 256, 0, stream>>>(scb);

        // o_b = P @ (VT)^T  (BM=128 -> 256 wgs, full chip)
        gemm8<128, 1><<<dim3(8, 32), 512, 0, stream>>>(
            (const unsigned short*)scb, nil, nil, 2 * SDIM,
            vT + b * (long)EDIM * SDIM, nil, nil, SDIM,
            qo + ro, EDIM, nullptr, 0, nullptr, 1.0f, SDIM, 1);
    }

    // 5) out = o @ o_w^T (2 segments: A*Bh, A*Bl); kb slot dead -> o_w split
    split_kernel<<<(long)EDIM * EDIM / 2048, 256, 0, stream>>>(o_w, owh, owl);
    gemm8<256, 0><<<dim3(8, 32), 512, 0, stream>>>(
        qo, qo, nil, EDIM, owh, owl, nil, EDIM,
        out, EDIM, nullptr, 0, nullptr, 1.0f, EDIM, 2);
}